// Round 1
// baseline (16389.000 us; speedup 1.0000x reference)
//
#include <hip/hip_runtime.h>
#include <cstdint>

// HashEncodingEnsemble: 16 tables x 16 levels x 2^19 entries x 2 feats (fp32)
// out[n, 2l+f] = sum_c w[n,l,c] * sum_t code[n,t] * T[t,l,h[n,l,c],f]

constexpr uint32_t TS    = 1u << 19;
constexpr uint32_t TMASK = TS - 1u;
constexpr uint32_t PR1   = 2654435761u;
constexpr uint32_t PR2   = 805459861u;

__global__ __launch_bounds__(256) void hash_ens_kernel(
    const float* __restrict__ xin,     // (N,3)
    const float* __restrict__ code,    // (N,16)
    const float* __restrict__ tables,  // (16,16,TS,2)
    float* __restrict__ out,           // (N,32)
    int N)
{
    const int n = blockIdx.x * 256 + threadIdx.x;
    if (n >= N) return;

    const float x0 = xin[3 * n + 0];
    const float x1 = xin[3 * n + 1];
    const float x2 = xin[3 * n + 2];

    // conditioning code for this point: 16 floats, 4x float4
    float cc[16];
    {
        const float4* c4 = reinterpret_cast<const float4*>(code + (size_t)n * 16);
        float4 a = c4[0], b = c4[1], c = c4[2], d = c4[3];
        cc[0] = a.x; cc[1] = a.y; cc[2]  = a.z; cc[3]  = a.w;
        cc[4] = b.x; cc[5] = b.y; cc[6]  = b.z; cc[7]  = b.w;
        cc[8] = c.x; cc[9] = c.y; cc[10] = c.z; cc[11] = c.w;
        cc[12] = d.x; cc[13] = d.y; cc[14] = d.z; cc[15] = d.w;
    }

    float o[32];

    double res_d = 16.0;  // BASE_RES * PER_LEVEL_SCALE^l, carried in double like the ref
    #pragma unroll 1
    for (int l = 0; l < 16; ++l) {
        const float res = (float)res_d;
        res_d *= 1.4472692012786865;

        const float pos0 = x0 * res, pos1 = x1 * res, pos2 = x2 * res;
        const float fl0 = floorf(pos0), fl1 = floorf(pos1), fl2 = floorf(pos2);
        const float fr0 = pos0 - fl0, fr1 = pos1 - fl1, fr2 = pos2 - fl2;
        const uint32_t i0 = (uint32_t)fl0, i1 = (uint32_t)fl1, i2 = (uint32_t)fl2;

        const uint32_t hx[2] = { i0,        i0 + 1u };
        const uint32_t hy[2] = { i1 * PR1,  i1 * PR1 + PR1 };
        const uint32_t hz[2] = { i2 * PR2,  i2 * PR2 + PR2 };
        const float    wx[2] = { 1.0f - fr0, fr0 };
        const float    wy[2] = { 1.0f - fr1, fr1 };
        const float    wz[2] = { 1.0f - fr2, fr2 };

        float acc0 = 0.0f, acc1 = 0.0f;

        #pragma unroll
        for (int cx = 0; cx < 2; ++cx) {
            #pragma unroll
            for (int cy = 0; cy < 2; ++cy) {
                #pragma unroll
                for (int cz = 0; cz < 2; ++cz) {
                    const uint32_t h = (hx[cx] ^ hy[cy] ^ hz[cz]) & TMASK;
                    const float    w = wx[cx] * wy[cy] * wz[cz];
                    // base of (t=0, level l, entry h)
                    const float* base = tables + ((size_t)l * TS + h) * 2u;
                    float s0 = 0.0f, s1 = 0.0f;
                    #pragma unroll
                    for (int t = 0; t < 16; ++t) {
                        const float2 v = *reinterpret_cast<const float2*>(
                            base + (size_t)t * (size_t)(16u * TS * 2u));
                        s0 = fmaf(cc[t], v.x, s0);
                        s1 = fmaf(cc[t], v.y, s1);
                    }
                    acc0 = fmaf(w, s0, acc0);
                    acc1 = fmaf(w, s1, acc1);
                }
            }
        }
        o[2 * l + 0] = acc0;
        o[2 * l + 1] = acc1;
    }

    float4*       o4 = reinterpret_cast<float4*>(out + (size_t)n * 32);
    const float4* oi = reinterpret_cast<const float4*>(o);
    #pragma unroll
    for (int i = 0; i < 8; ++i) o4[i] = oi[i];
}

extern "C" void kernel_launch(void* const* d_in, const int* in_sizes, int n_in,
                              void* d_out, int out_size, void* d_ws, size_t ws_size,
                              hipStream_t stream) {
    const float* xin    = (const float*)d_in[0];  // in_tensor (N,3)
    const float* code   = (const float*)d_in[1];  // conditioning_code (N,16)
    const float* tables = (const float*)d_in[2];  // tables (16,16,2^19,2)
    float*       out    = (float*)d_out;          // (N,32)

    const int N = in_sizes[0] / 3;
    const int block = 256;
    const int grid  = (N + block - 1) / block;
    hipLaunchKernelGGL(hash_ens_kernel, dim3(grid), dim3(block), 0, stream,
                       xin, code, tables, out, N);
}

// Round 2
// 4827.411 us; speedup vs baseline: 3.3950x; 3.3950x over previous
//
#include <hip/hip_runtime.h>
#include <cstdint>

// HashEncodingEnsemble: 16 tables x 16 levels x 2^19 entries x 2 feats (fp32)
// out[n, 2l+f] = sum_c w[n,l,c] * sum_t code[n,t] * T[t,l,h[n,l,c],f]
//
// Strategy: transpose tables into ws as [l][h][t][f] so each (level, corner)
// gather is one fully-used 128 B contiguous read instead of 16 scattered 8 B
// reads (each of which pulled a whole 64 B line -> 50x overfetch in round 1).

constexpr uint32_t TS    = 1u << 19;
constexpr uint32_t TMASK = TS - 1u;
constexpr uint32_t PR1   = 2654435761u;
constexpr uint32_t PR2   = 805459861u;
constexpr int NT = 16;  // tables
constexpr int NL = 16;  // levels

// ---------------------------------------------------------------- transpose
// wsT[l][h][t][f] <- tables[t][l][h][f]; one thread per h (per level).
// Reads: for fixed t, consecutive threads read consecutive float2 (coalesced).
// Writes: 128 B contiguous per thread (perfectly coalesced, line-aligned).

__global__ __launch_bounds__(256) void transpose_full(
    const float* __restrict__ tables, float* __restrict__ wsT)
{
    const uint32_t h = blockIdx.x * 256 + threadIdx.x;
    const uint32_t l = blockIdx.y;
    float2 v[NT];
    #pragma unroll
    for (int t = 0; t < NT; ++t)
        v[t] = *reinterpret_cast<const float2*>(
            tables + (((size_t)t * NL + l) * TS + h) * 2u);
    float4* dst = reinterpret_cast<float4*>(wsT + ((size_t)l * TS + h) * 32u);
    #pragma unroll
    for (int j = 0; j < 8; ++j)
        dst[j] = make_float4(v[2*j].x, v[2*j].y, v[2*j+1].x, v[2*j+1].y);
}

__global__ __launch_bounds__(256) void transpose_level(
    const float* __restrict__ tables, float* __restrict__ wsL, int l)
{
    const uint32_t h = blockIdx.x * 256 + threadIdx.x;
    float2 v[NT];
    #pragma unroll
    for (int t = 0; t < NT; ++t)
        v[t] = *reinterpret_cast<const float2*>(
            tables + (((size_t)t * NL + l) * TS + h) * 2u);
    float4* dst = reinterpret_cast<float4*>(wsL + (size_t)h * 32u);
    #pragma unroll
    for (int j = 0; j < 8; ++j)
        dst[j] = make_float4(v[2*j].x, v[2*j].y, v[2*j+1].x, v[2*j+1].y);
}

// ---------------------------------------------------------------- gather
// Per point, per corner: one 128 B contiguous read (8x float4) from wsT,
// dot with conditioning code, trilinear-weight, store 2 floats per level.

__device__ __forceinline__ void gather_one_level(
    const float* __restrict__ lvl,   // transposed level slice base [h][t][f]
    float x0, float x1, float x2, float res,
    const float* cc, float* out2)
{
    const float pos0 = x0 * res, pos1 = x1 * res, pos2 = x2 * res;
    const float fl0 = floorf(pos0), fl1 = floorf(pos1), fl2 = floorf(pos2);
    const float fr0 = pos0 - fl0, fr1 = pos1 - fl1, fr2 = pos2 - fl2;
    const uint32_t i0 = (uint32_t)fl0, i1 = (uint32_t)fl1, i2 = (uint32_t)fl2;

    const uint32_t hx[2] = { i0,       i0 + 1u };
    const uint32_t hy[2] = { i1 * PR1, i1 * PR1 + PR1 };
    const uint32_t hz[2] = { i2 * PR2, i2 * PR2 + PR2 };
    const float    wx[2] = { 1.0f - fr0, fr0 };
    const float    wy[2] = { 1.0f - fr1, fr1 };
    const float    wz[2] = { 1.0f - fr2, fr2 };

    float acc0 = 0.0f, acc1 = 0.0f;
    #pragma unroll
    for (int cx = 0; cx < 2; ++cx)
    #pragma unroll
    for (int cy = 0; cy < 2; ++cy)
    #pragma unroll
    for (int cz = 0; cz < 2; ++cz) {
        const uint32_t h = (hx[cx] ^ hy[cy] ^ hz[cz]) & TMASK;
        const float    w = wx[cx] * wy[cy] * wz[cz];
        const float4* base = reinterpret_cast<const float4*>(lvl + (size_t)h * 32u);
        float s0 = 0.0f, s1 = 0.0f;
        #pragma unroll
        for (int j = 0; j < 8; ++j) {
            const float4 v = base[j];
            s0 = fmaf(cc[2*j], v.x, fmaf(cc[2*j+1], v.z, s0));
            s1 = fmaf(cc[2*j], v.y, fmaf(cc[2*j+1], v.w, s1));
        }
        acc0 = fmaf(w, s0, acc0);
        acc1 = fmaf(w, s1, acc1);
    }
    out2[0] = acc0;
    out2[1] = acc1;
}

__device__ __forceinline__ void load_cc(const float* __restrict__ code, int n, float* cc)
{
    const float4* c4 = reinterpret_cast<const float4*>(code + (size_t)n * 16);
    float4 a = c4[0], b = c4[1], c = c4[2], d = c4[3];
    cc[0]=a.x; cc[1]=a.y; cc[2]=a.z;  cc[3]=a.w;
    cc[4]=b.x; cc[5]=b.y; cc[6]=b.z;  cc[7]=b.w;
    cc[8]=c.x; cc[9]=c.y; cc[10]=c.z; cc[11]=c.w;
    cc[12]=d.x; cc[13]=d.y; cc[14]=d.z; cc[15]=d.w;
}

__global__ __launch_bounds__(256) void gather_full(
    const float* __restrict__ xin, const float* __restrict__ code,
    const float* __restrict__ wsT, float* __restrict__ out, int N)
{
    const int n = blockIdx.x * 256 + threadIdx.x;
    if (n >= N) return;
    const float x0 = xin[3*n+0], x1 = xin[3*n+1], x2 = xin[3*n+2];
    float cc[16];
    load_cc(code, n, cc);

    double res_d = 16.0;
    #pragma unroll 1
    for (int l = 0; l < NL; ++l) {
        const float res = (float)res_d;
        res_d *= 1.4472692012786865;
        float o2[2];
        gather_one_level(wsT + (size_t)l * TS * 32u, x0, x1, x2, res, cc, o2);
        out[(size_t)n * 32 + 2*l + 0] = o2[0];
        out[(size_t)n * 32 + 2*l + 1] = o2[1];
    }
}

__global__ __launch_bounds__(256) void gather_level(
    const float* __restrict__ xin, const float* __restrict__ code,
    const float* __restrict__ wsL, float* __restrict__ out, int N,
    int l, float res)
{
    const int n = blockIdx.x * 256 + threadIdx.x;
    if (n >= N) return;
    const float x0 = xin[3*n+0], x1 = xin[3*n+1], x2 = xin[3*n+2];
    float cc[16];
    load_cc(code, n, cc);
    float o2[2];
    gather_one_level(wsL, x0, x1, x2, res, cc, o2);
    out[(size_t)n * 32 + 2*l + 0] = o2[0];
    out[(size_t)n * 32 + 2*l + 1] = o2[1];
}

// ---------------------------------------------------------------- fallback
// Round-1 baseline (direct gather from original layout), used only if ws is
// too small for even one transposed level slice.

__global__ __launch_bounds__(256) void hash_ens_baseline(
    const float* __restrict__ xin, const float* __restrict__ code,
    const float* __restrict__ tables, float* __restrict__ out, int N)
{
    const int n = blockIdx.x * 256 + threadIdx.x;
    if (n >= N) return;
    const float x0 = xin[3*n+0], x1 = xin[3*n+1], x2 = xin[3*n+2];
    float cc[16];
    load_cc(code, n, cc);

    double res_d = 16.0;
    #pragma unroll 1
    for (int l = 0; l < NL; ++l) {
        const float res = (float)res_d;
        res_d *= 1.4472692012786865;
        const float pos0 = x0*res, pos1 = x1*res, pos2 = x2*res;
        const float fl0 = floorf(pos0), fl1 = floorf(pos1), fl2 = floorf(pos2);
        const float fr0 = pos0-fl0, fr1 = pos1-fl1, fr2 = pos2-fl2;
        const uint32_t i0 = (uint32_t)fl0, i1 = (uint32_t)fl1, i2 = (uint32_t)fl2;
        const uint32_t hx[2] = { i0, i0+1u };
        const uint32_t hy[2] = { i1*PR1, i1*PR1+PR1 };
        const uint32_t hz[2] = { i2*PR2, i2*PR2+PR2 };
        const float wx[2] = { 1.0f-fr0, fr0 };
        const float wy[2] = { 1.0f-fr1, fr1 };
        const float wz[2] = { 1.0f-fr2, fr2 };
        float acc0 = 0.0f, acc1 = 0.0f;
        #pragma unroll
        for (int cx = 0; cx < 2; ++cx)
        #pragma unroll
        for (int cy = 0; cy < 2; ++cy)
        #pragma unroll
        for (int cz = 0; cz < 2; ++cz) {
            const uint32_t h = (hx[cx]^hy[cy]^hz[cz]) & TMASK;
            const float w = wx[cx]*wy[cy]*wz[cz];
            const float* base = tables + ((size_t)l * TS + h) * 2u;
            float s0 = 0.0f, s1 = 0.0f;
            #pragma unroll
            for (int t = 0; t < NT; ++t) {
                const float2 v = *reinterpret_cast<const float2*>(
                    base + (size_t)t * (size_t)(NL * TS * 2u));
                s0 = fmaf(cc[t], v.x, s0);
                s1 = fmaf(cc[t], v.y, s1);
            }
            acc0 = fmaf(w, s0, acc0);
            acc1 = fmaf(w, s1, acc1);
        }
        out[(size_t)n * 32 + 2*l + 0] = acc0;
        out[(size_t)n * 32 + 2*l + 1] = acc1;
    }
}

// ---------------------------------------------------------------- launcher

extern "C" void kernel_launch(void* const* d_in, const int* in_sizes, int n_in,
                              void* d_out, int out_size, void* d_ws, size_t ws_size,
                              hipStream_t stream) {
    const float* xin    = (const float*)d_in[0];  // (N,3)
    const float* code   = (const float*)d_in[1];  // (N,16)
    const float* tables = (const float*)d_in[2];  // (16,16,2^19,2)
    float*       out    = (float*)d_out;          // (N,32)
    float*       ws     = (float*)d_ws;

    const int N = in_sizes[0] / 3;
    const int block = 256;
    const int gridN = (N + block - 1) / block;

    const size_t full_bytes = (size_t)NL * TS * NT * 2 * sizeof(float); // 1 GiB
    const size_t lvl_bytes  = (size_t)TS * NT * 2 * sizeof(float);      // 64 MiB

    if (ws_size >= full_bytes) {
        hipLaunchKernelGGL(transpose_full, dim3(TS / 256, NL), dim3(block), 0, stream,
                           tables, ws);
        hipLaunchKernelGGL(gather_full, dim3(gridN), dim3(block), 0, stream,
                           xin, code, ws, out, N);
    } else if (ws_size >= lvl_bytes) {
        double res_d = 16.0;
        for (int l = 0; l < NL; ++l) {
            const float res = (float)res_d;
            res_d *= 1.4472692012786865;
            hipLaunchKernelGGL(transpose_level, dim3(TS / 256), dim3(block), 0, stream,
                               tables, ws, l);
            hipLaunchKernelGGL(gather_level, dim3(gridN), dim3(block), 0, stream,
                               xin, code, ws, out, N, l, res);
        }
    } else {
        hipLaunchKernelGGL(hash_ens_baseline, dim3(gridN), dim3(block), 0, stream,
                           xin, code, tables, out, N);
    }
}

// Round 3
// 1292.804 us; speedup vs baseline: 12.6771x; 3.7341x over previous
//
#include <hip/hip_runtime.h>
#include <hip/hip_fp16.h>
#include <cstdint>

// HashEncodingEnsemble: 16 tables x 16 levels x 2^19 entries x 2 feats (fp32)
// out[n, 2l+f] = sum_c w[n,l,c] * sum_t code[n,t] * T[t,l,h[n,l,c],f]
//
// Round 3 strategy:
//  - transpose+convert tables into ws as fp16 [l][h][f][t]: 64 B per (l,h),
//    one 4x dwordx4 gather per corner (was 128 B fp32).
//  - gather in 8 sequential launches of 2 levels each: per-launch working set
//    = 2 x 32 MiB slices -> L3-resident, the 8x per-entry reuse becomes L3
//    hits instead of HBM re-fetches (round 2: 14.5 GB fetch vs 8.6 GB useful).

constexpr uint32_t TS    = 1u << 19;
constexpr uint32_t TMASK = TS - 1u;
constexpr uint32_t PR1   = 2654435761u;
constexpr uint32_t PR2   = 805459861u;
constexpr int NT = 16;  // tables
constexpr int NL = 16;  // levels

// ---------------------------------------------------------------- transpose
// wsT[l][h][f][t] (fp16) <- tables[t][l][h][f] (fp32).
// Word layout per (l,h): 16 uint32 words; word j (j<8) = f0 halves (t=2j,2j+1),
// word 8+j = f1 halves (t=2j,2j+1).

__global__ __launch_bounds__(256) void transpose_f16(
    const float* __restrict__ tables, __half* __restrict__ wsT)
{
    const uint32_t h = blockIdx.x * 256 + threadIdx.x;
    const uint32_t l = blockIdx.y;
    float2 v[NT];
    #pragma unroll
    for (int t = 0; t < NT; ++t)
        v[t] = *reinterpret_cast<const float2*>(
            tables + (((size_t)t * NL + l) * TS + h) * 2u);
    uint32_t w[16];
    #pragma unroll
    for (int j = 0; j < 8; ++j) {
        __half2 a = __floats2half2_rn(v[2*j].x, v[2*j+1].x);  // f0: t=2j, 2j+1
        __half2 b = __floats2half2_rn(v[2*j].y, v[2*j+1].y);  // f1: t=2j, 2j+1
        w[j]     = *reinterpret_cast<uint32_t*>(&a);
        w[8 + j] = *reinterpret_cast<uint32_t*>(&b);
    }
    uint4* dst = reinterpret_cast<uint4*>(wsT + ((size_t)l * TS + h) * 32u);
    dst[0] = make_uint4(w[0],  w[1],  w[2],  w[3]);
    dst[1] = make_uint4(w[4],  w[5],  w[6],  w[7]);
    dst[2] = make_uint4(w[8],  w[9],  w[10], w[11]);
    dst[3] = make_uint4(w[12], w[13], w[14], w[15]);
}

// ---------------------------------------------------------------- gather

__device__ __forceinline__ float acc_word(uint32_t wd, float c0, float c1, float s)
{
    const __half2 h2 = *reinterpret_cast<const __half2*>(&wd);
    const float2  f  = __half22float2(h2);
    return fmaf(c1, f.y, fmaf(c0, f.x, s));
}

__device__ __forceinline__ void load_cc(const float* __restrict__ code, int n, float* cc)
{
    const float4* c4 = reinterpret_cast<const float4*>(code + (size_t)n * 16);
    float4 a = c4[0], b = c4[1], c = c4[2], d = c4[3];
    cc[0]=a.x;  cc[1]=a.y;  cc[2]=a.z;   cc[3]=a.w;
    cc[4]=b.x;  cc[5]=b.y;  cc[6]=b.z;   cc[7]=b.w;
    cc[8]=c.x;  cc[9]=c.y;  cc[10]=c.z;  cc[11]=c.w;
    cc[12]=d.x; cc[13]=d.y; cc[14]=d.z;  cc[15]=d.w;
}

__device__ __forceinline__ void gather_level_f16(
    const __half* __restrict__ lvl,   // [h][f][t] fp16, 64 B per h
    float x0, float x1, float x2, float res,
    const float* cc, float* out2)
{
    const float pos0 = x0 * res, pos1 = x1 * res, pos2 = x2 * res;
    const float fl0 = floorf(pos0), fl1 = floorf(pos1), fl2 = floorf(pos2);
    const float fr0 = pos0 - fl0, fr1 = pos1 - fl1, fr2 = pos2 - fl2;
    const uint32_t i0 = (uint32_t)fl0, i1 = (uint32_t)fl1, i2 = (uint32_t)fl2;

    const uint32_t hx[2] = { i0,       i0 + 1u };
    const uint32_t hy[2] = { i1 * PR1, i1 * PR1 + PR1 };
    const uint32_t hz[2] = { i2 * PR2, i2 * PR2 + PR2 };
    const float    wx[2] = { 1.0f - fr0, fr0 };
    const float    wy[2] = { 1.0f - fr1, fr1 };
    const float    wz[2] = { 1.0f - fr2, fr2 };

    float acc0 = 0.0f, acc1 = 0.0f;
    #pragma unroll
    for (int cx = 0; cx < 2; ++cx)
    #pragma unroll
    for (int cy = 0; cy < 2; ++cy)
    #pragma unroll
    for (int cz = 0; cz < 2; ++cz) {
        const uint32_t h = (hx[cx] ^ hy[cy] ^ hz[cz]) & TMASK;
        const float    w = wx[cx] * wy[cy] * wz[cz];
        const uint4* base = reinterpret_cast<const uint4*>(lvl + (size_t)h * 32u);
        const uint4 q0 = base[0];  // f0 words 0..3  (t0..7)
        const uint4 q1 = base[1];  // f0 words 4..7  (t8..15)
        const uint4 q2 = base[2];  // f1 words 0..3
        const uint4 q3 = base[3];  // f1 words 4..7
        float s0 = 0.0f, s1 = 0.0f;
        s0 = acc_word(q0.x, cc[0],  cc[1],  s0);
        s0 = acc_word(q0.y, cc[2],  cc[3],  s0);
        s0 = acc_word(q0.z, cc[4],  cc[5],  s0);
        s0 = acc_word(q0.w, cc[6],  cc[7],  s0);
        s0 = acc_word(q1.x, cc[8],  cc[9],  s0);
        s0 = acc_word(q1.y, cc[10], cc[11], s0);
        s0 = acc_word(q1.z, cc[12], cc[13], s0);
        s0 = acc_word(q1.w, cc[14], cc[15], s0);
        s1 = acc_word(q2.x, cc[0],  cc[1],  s1);
        s1 = acc_word(q2.y, cc[2],  cc[3],  s1);
        s1 = acc_word(q2.z, cc[4],  cc[5],  s1);
        s1 = acc_word(q2.w, cc[6],  cc[7],  s1);
        s1 = acc_word(q3.x, cc[8],  cc[9],  s1);
        s1 = acc_word(q3.y, cc[10], cc[11], s1);
        s1 = acc_word(q3.z, cc[12], cc[13], s1);
        s1 = acc_word(q3.w, cc[14], cc[15], s1);
        acc0 = fmaf(w, s0, acc0);
        acc1 = fmaf(w, s1, acc1);
    }
    out2[0] = acc0;
    out2[1] = acc1;
}

// One launch handles 2 levels; writes one aligned float4 per point.
__global__ __launch_bounds__(256) void gather_pair(
    const float* __restrict__ xin, const float* __restrict__ code,
    const __half* __restrict__ ws2,   // base of level-pair slice [2][TS][32]
    float* __restrict__ out, int N, int l0, float res0, float res1)
{
    const int n = blockIdx.x * 256 + threadIdx.x;
    if (n >= N) return;
    const float x0 = xin[3*n+0], x1 = xin[3*n+1], x2 = xin[3*n+2];
    float cc[16];
    load_cc(code, n, cc);

    float o4[4];
    gather_level_f16(ws2,                     x0, x1, x2, res0, cc, o4 + 0);
    gather_level_f16(ws2 + (size_t)TS * 32u,  x0, x1, x2, res1, cc, o4 + 2);

    *reinterpret_cast<float4*>(out + (size_t)n * 32 + 2 * l0) =
        *reinterpret_cast<const float4*>(o4);
}

// ---------------------------------------------------------------- fallback
// Round-1 baseline (direct gather from original layout), used only if ws is
// too small for the fp16 transposed table.

__global__ __launch_bounds__(256) void hash_ens_baseline(
    const float* __restrict__ xin, const float* __restrict__ code,
    const float* __restrict__ tables, float* __restrict__ out, int N)
{
    const int n = blockIdx.x * 256 + threadIdx.x;
    if (n >= N) return;
    const float x0 = xin[3*n+0], x1 = xin[3*n+1], x2 = xin[3*n+2];
    float cc[16];
    load_cc(code, n, cc);

    double res_d = 16.0;
    #pragma unroll 1
    for (int l = 0; l < NL; ++l) {
        const float res = (float)res_d;
        res_d *= 1.4472692012786865;
        const float pos0 = x0*res, pos1 = x1*res, pos2 = x2*res;
        const float fl0 = floorf(pos0), fl1 = floorf(pos1), fl2 = floorf(pos2);
        const float fr0 = pos0-fl0, fr1 = pos1-fl1, fr2 = pos2-fl2;
        const uint32_t i0 = (uint32_t)fl0, i1 = (uint32_t)fl1, i2 = (uint32_t)fl2;
        const uint32_t hx[2] = { i0, i0+1u };
        const uint32_t hy[2] = { i1*PR1, i1*PR1+PR1 };
        const uint32_t hz[2] = { i2*PR2, i2*PR2+PR2 };
        const float wx[2] = { 1.0f-fr0, fr0 };
        const float wy[2] = { 1.0f-fr1, fr1 };
        const float wz[2] = { 1.0f-fr2, fr2 };
        float acc0 = 0.0f, acc1 = 0.0f;
        #pragma unroll
        for (int cx = 0; cx < 2; ++cx)
        #pragma unroll
        for (int cy = 0; cy < 2; ++cy)
        #pragma unroll
        for (int cz = 0; cz < 2; ++cz) {
            const uint32_t h = (hx[cx]^hy[cy]^hz[cz]) & TMASK;
            const float w = wx[cx]*wy[cy]*wz[cz];
            const float* base = tables + ((size_t)l * TS + h) * 2u;
            float s0 = 0.0f, s1 = 0.0f;
            #pragma unroll
            for (int t = 0; t < NT; ++t) {
                const float2 v = *reinterpret_cast<const float2*>(
                    base + (size_t)t * (size_t)(NL * TS * 2u));
                s0 = fmaf(cc[t], v.x, s0);
                s1 = fmaf(cc[t], v.y, s1);
            }
            acc0 = fmaf(w, s0, acc0);
            acc1 = fmaf(w, s1, acc1);
        }
        out[(size_t)n * 32 + 2*l + 0] = acc0;
        out[(size_t)n * 32 + 2*l + 1] = acc1;
    }
}

// ---------------------------------------------------------------- launcher

extern "C" void kernel_launch(void* const* d_in, const int* in_sizes, int n_in,
                              void* d_out, int out_size, void* d_ws, size_t ws_size,
                              hipStream_t stream) {
    const float* xin    = (const float*)d_in[0];  // (N,3)
    const float* code   = (const float*)d_in[1];  // (N,16)
    const float* tables = (const float*)d_in[2];  // (16,16,2^19,2)
    float*       out    = (float*)d_out;          // (N,32)

    const int N = in_sizes[0] / 3;
    const int block = 256;
    const int gridN = (N + block - 1) / block;

    const size_t f16_bytes = (size_t)NL * TS * 2 * NT * sizeof(__half); // 512 MiB

    if (ws_size >= f16_bytes) {
        __half* wsT = (__half*)d_ws;
        hipLaunchKernelGGL(transpose_f16, dim3(TS / 256, NL), dim3(block), 0, stream,
                           tables, wsT);
        // level resolutions, iterated double product (matches prior passing rounds)
        float resv[NL];
        double res_d = 16.0;
        for (int l = 0; l < NL; ++l) { resv[l] = (float)res_d; res_d *= 1.4472692012786865; }
        for (int l0 = 0; l0 < NL; l0 += 2) {
            hipLaunchKernelGGL(gather_pair, dim3(gridN), dim3(block), 0, stream,
                               xin, code, wsT + (size_t)l0 * TS * 32u, out, N,
                               l0, resv[l0], resv[l0 + 1]);
        }
    } else {
        hipLaunchKernelGGL(hash_ens_baseline, dim3(gridN), dim3(block), 0, stream,
                           xin, code, tables, out, N);
    }
}

// Round 4
// 1125.983 us; speedup vs baseline: 14.5553x; 1.1482x over previous
//
#include <hip/hip_runtime.h>
#include <hip/hip_fp16.h>
#include <cstdint>

// HashEncodingEnsemble: 16 tables x 16 levels x 2^19 entries x 2 feats (fp32)
// out[n, 2l+f] = sum_c w[n,l,c] * sum_t code[n,t] * T[t,l,h[n,l,c],f]
//
// Round 4:
//  - fp16 transposed table in ws: [l][h][t] where word t = half2(f0,f1).
//  - cooperative gather: 4 consecutive lanes load one corner's 64 B entry
//    (16 B chunk each) -> TA coalesces to 1 line-probe per corner (was 4).
//    One wave-inst = 2 points x 8 corners. shfl_xor butterfly reduces the
//    per-chunk dot products within each 32-lane half.
//  - 4 levels per gather launch (128 MiB slice set, L3-resident), all 4
//    level-gathers in flight per iteration for MLP.

constexpr uint32_t TS    = 1u << 19;
constexpr uint32_t TMASK = TS - 1u;
constexpr uint32_t PR1   = 2654435761u;
constexpr uint32_t PR2   = 805459861u;
constexpr int NT = 16;  // tables
constexpr int NL = 16;  // levels

// ---------------------------------------------------------------- transpose
// wsT[l][h] = 16 words; word t = half2(feat0, feat1) of table t.

__global__ __launch_bounds__(256) void transpose_f16(
    const float* __restrict__ tables, uint32_t* __restrict__ wsT)
{
    const uint32_t h = blockIdx.x * 256 + threadIdx.x;
    const uint32_t l = blockIdx.y;
    uint32_t w[NT];
    #pragma unroll
    for (int t = 0; t < NT; ++t) {
        const float2 v = *reinterpret_cast<const float2*>(
            tables + (((size_t)t * NL + l) * TS + h) * 2u);
        const __half2 p = __floats2half2_rn(v.x, v.y);
        w[t] = *reinterpret_cast<const uint32_t*>(&p);
    }
    uint4* dst = reinterpret_cast<uint4*>(wsT + ((size_t)l * TS + h) * 16u);
    dst[0] = make_uint4(w[0],  w[1],  w[2],  w[3]);
    dst[1] = make_uint4(w[4],  w[5],  w[6],  w[7]);
    dst[2] = make_uint4(w[8],  w[9],  w[10], w[11]);
    dst[3] = make_uint4(w[12], w[13], w[14], w[15]);
}

// ---------------------------------------------------------------- gather
// Lane roles within a wave: c = lane&3 (16 B chunk = tables 4c..4c+3),
// k = (lane>>2)&7 (corner), half = lane>>5 (which point of the pair).

__device__ __forceinline__ float2 chunk_dot(const uint4 q, const float4 cc)
{
    float s0 = 0.0f, s1 = 0.0f;
    const uint32_t wd[4] = { q.x, q.y, q.z, q.w };
    const float    cv[4] = { cc.x, cc.y, cc.z, cc.w };
    #pragma unroll
    for (int j = 0; j < 4; ++j) {
        const __half2 h2 = *reinterpret_cast<const __half2*>(&wd[j]);
        const float2  f  = __half22float2(h2);
        s0 = fmaf(cv[j], f.x, s0);
        s1 = fmaf(cv[j], f.y, s1);
    }
    return make_float2(s0, s1);
}

__global__ __launch_bounds__(256) void gather4(
    const float* __restrict__ xin, const float* __restrict__ code,
    const uint32_t* __restrict__ ws4,   // [4][TS][16 words], levels l0..l0+3
    float* __restrict__ out, int Npairs, int l0, float4 resv)
{
    const int lane  = threadIdx.x & 63;
    const int gwave = (blockIdx.x * 256 + threadIdx.x) >> 6;
    const int nwave = (gridDim.x * 256) >> 6;

    const uint32_t c  = lane & 3;
    const uint32_t k  = (lane >> 2) & 7;
    const int      hf = lane >> 5;
    const uint32_t cx = k & 1, cy = (k >> 1) & 1, cz = (k >> 2) & 1;
    const uint32_t cyp = cy ? PR1 : 0u;
    const uint32_t czp = cz ? PR2 : 0u;

    const float res[4] = { resv.x, resv.y, resv.z, resv.w };

    for (int pp = gwave; pp < Npairs; pp += nwave) {
        const int p = 2 * pp + hf;
        const float x0 = xin[3 * p + 0];
        const float x1 = xin[3 * p + 1];
        const float x2 = xin[3 * p + 2];
        const float4 cc = *reinterpret_cast<const float4*>(
            code + (size_t)p * 16 + 4 * c);

        // phase 1: hashes + weights + issue all 4 level gathers
        uint4 q[4];
        float wgt[4];
        #pragma unroll
        for (int li = 0; li < 4; ++li) {
            const float pos0 = x0 * res[li], pos1 = x1 * res[li], pos2 = x2 * res[li];
            const float fl0 = floorf(pos0), fl1 = floorf(pos1), fl2 = floorf(pos2);
            const float fr0 = pos0 - fl0, fr1 = pos1 - fl1, fr2 = pos2 - fl2;
            const uint32_t i0 = (uint32_t)fl0, i1 = (uint32_t)fl1, i2 = (uint32_t)fl2;
            const uint32_t h = ((i0 + cx) ^ (i1 * PR1 + cyp) ^ (i2 * PR2 + czp)) & TMASK;
            q[li] = *reinterpret_cast<const uint4*>(
                ws4 + ((size_t)li * TS + h) * 16u + 4u * c);
            wgt[li] = (cx ? fr0 : 1.0f - fr0) *
                      (cy ? fr1 : 1.0f - fr1) *
                      (cz ? fr2 : 1.0f - fr2);
        }

        // phase 2: dot, weight, butterfly-reduce within each 32-lane half
        float o[8];
        #pragma unroll
        for (int li = 0; li < 4; ++li) {
            const float2 s = chunk_dot(q[li], cc);
            float r0 = wgt[li] * s.x;
            float r1 = wgt[li] * s.y;
            #pragma unroll
            for (int m = 1; m <= 16; m <<= 1) {
                r0 += __shfl_xor(r0, m);
                r1 += __shfl_xor(r1, m);
            }
            o[2 * li + 0] = r0;
            o[2 * li + 1] = r1;
        }

        if ((lane & 31) == 0) {
            float4* op = reinterpret_cast<float4*>(out + (size_t)p * 32 + 2 * l0);
            op[0] = make_float4(o[0], o[1], o[2], o[3]);
            op[1] = make_float4(o[4], o[5], o[6], o[7]);
        }
    }
}

// ---------------------------------------------------------------- fallback
// Direct gather from the original layout (used only if ws < 512 MiB).

__device__ __forceinline__ void load_cc16(const float* __restrict__ code, int n, float* cc)
{
    const float4* c4 = reinterpret_cast<const float4*>(code + (size_t)n * 16);
    float4 a = c4[0], b = c4[1], c = c4[2], d = c4[3];
    cc[0]=a.x;  cc[1]=a.y;  cc[2]=a.z;   cc[3]=a.w;
    cc[4]=b.x;  cc[5]=b.y;  cc[6]=b.z;   cc[7]=b.w;
    cc[8]=c.x;  cc[9]=c.y;  cc[10]=c.z;  cc[11]=c.w;
    cc[12]=d.x; cc[13]=d.y; cc[14]=d.z;  cc[15]=d.w;
}

__global__ __launch_bounds__(256) void hash_ens_baseline(
    const float* __restrict__ xin, const float* __restrict__ code,
    const float* __restrict__ tables, float* __restrict__ out, int N)
{
    const int n = blockIdx.x * 256 + threadIdx.x;
    if (n >= N) return;
    const float x0 = xin[3*n+0], x1 = xin[3*n+1], x2 = xin[3*n+2];
    float cc[16];
    load_cc16(code, n, cc);

    double res_d = 16.0;
    #pragma unroll 1
    for (int l = 0; l < NL; ++l) {
        const float res = (float)res_d;
        res_d *= 1.4472692012786865;
        const float pos0 = x0*res, pos1 = x1*res, pos2 = x2*res;
        const float fl0 = floorf(pos0), fl1 = floorf(pos1), fl2 = floorf(pos2);
        const float fr0 = pos0-fl0, fr1 = pos1-fl1, fr2 = pos2-fl2;
        const uint32_t i0 = (uint32_t)fl0, i1 = (uint32_t)fl1, i2 = (uint32_t)fl2;
        const uint32_t hx[2] = { i0, i0+1u };
        const uint32_t hy[2] = { i1*PR1, i1*PR1+PR1 };
        const uint32_t hz[2] = { i2*PR2, i2*PR2+PR2 };
        const float wx[2] = { 1.0f-fr0, fr0 };
        const float wy[2] = { 1.0f-fr1, fr1 };
        const float wz[2] = { 1.0f-fr2, fr2 };
        float acc0 = 0.0f, acc1 = 0.0f;
        #pragma unroll
        for (int cxx = 0; cxx < 2; ++cxx)
        #pragma unroll
        for (int cyy = 0; cyy < 2; ++cyy)
        #pragma unroll
        for (int czz = 0; czz < 2; ++czz) {
            const uint32_t h = (hx[cxx]^hy[cyy]^hz[czz]) & TMASK;
            const float w = wx[cxx]*wy[cyy]*wz[czz];
            const float* base = tables + ((size_t)l * TS + h) * 2u;
            float s0 = 0.0f, s1 = 0.0f;
            #pragma unroll
            for (int t = 0; t < NT; ++t) {
                const float2 v = *reinterpret_cast<const float2*>(
                    base + (size_t)t * (size_t)(NL * TS * 2u));
                s0 = fmaf(cc[t], v.x, s0);
                s1 = fmaf(cc[t], v.y, s1);
            }
            acc0 = fmaf(w, s0, acc0);
            acc1 = fmaf(w, s1, acc1);
        }
        out[(size_t)n * 32 + 2*l + 0] = acc0;
        out[(size_t)n * 32 + 2*l + 1] = acc1;
    }
}

// ---------------------------------------------------------------- launcher

extern "C" void kernel_launch(void* const* d_in, const int* in_sizes, int n_in,
                              void* d_out, int out_size, void* d_ws, size_t ws_size,
                              hipStream_t stream) {
    const float* xin    = (const float*)d_in[0];  // (N,3)
    const float* code   = (const float*)d_in[1];  // (N,16)
    const float* tables = (const float*)d_in[2];  // (16,16,2^19,2)
    float*       out    = (float*)d_out;          // (N,32)

    const int N = in_sizes[0] / 3;
    const int block = 256;

    const size_t f16_bytes = (size_t)NL * TS * NT * sizeof(uint32_t) / 2; // 512 MiB
    // (NL*TS entries x 16 words x 4 B = 512 MiB)

    if (ws_size >= (size_t)NL * TS * 16u * 4u) {
        uint32_t* wsT = (uint32_t*)d_ws;
        hipLaunchKernelGGL(transpose_f16, dim3(TS / 256, NL), dim3(block), 0, stream,
                           tables, wsT);

        float resv[NL];
        double res_d = 16.0;
        for (int l = 0; l < NL; ++l) { resv[l] = (float)res_d; res_d *= 1.4472692012786865; }

        const int Npairs = N / 2;
        const int grid   = 2048;  // 8 blocks/CU x 256 CUs; grid-stride over pairs
        for (int l0 = 0; l0 < NL; l0 += 4) {
            hipLaunchKernelGGL(gather4, dim3(grid), dim3(block), 0, stream,
                               xin, code, wsT + (size_t)l0 * TS * 16u, out, Npairs, l0,
                               make_float4(resv[l0], resv[l0+1], resv[l0+2], resv[l0+3]));
        }
        (void)f16_bytes;
    } else {
        const int gridN = (N + block - 1) / block;
        hipLaunchKernelGGL(hash_ens_baseline, dim3(gridN), dim3(block), 0, stream,
                           xin, code, tables, out, N);
    }
}